// Round 7
// baseline (2700.303 us; speedup 1.0000x reference)
//
#include <hip/hip_runtime.h>
#include <cstddef>

#define BATCH 32
#define TLEN  2048
#define HDIM  256
#define KDIM  512   // IX + IH
#define NDIM  1024  // 4 gates * H

typedef float f32x4 __attribute__((ext_vector_type(4)));

// ---------------- pack weights: Wp[k][n], k in [0,512), n = gate*256 + j ----------------
__global__ void pack_w_kernel(const float* __restrict__ wix, const float* __restrict__ wih,
                              const float* __restrict__ wfx, const float* __restrict__ wfh,
                              const float* __restrict__ wcx, const float* __restrict__ wch,
                              const float* __restrict__ wox, const float* __restrict__ woh,
                              float* __restrict__ Wp) {
  int idx = blockIdx.x * blockDim.x + threadIdx.x;
  if (idx >= KDIM * NDIM) return;
  int n = idx & (NDIM - 1);
  int k = idx >> 10;
  int gate = n >> 8;
  int j = n & 255;
  const float* sx; const float* sh;
  if (gate == 0)      { sx = wix; sh = wih; }
  else if (gate == 1) { sx = wfx; sh = wfh; }
  else if (gate == 2) { sx = wcx; sh = wch; }
  else                { sx = wox; sh = woh; }
  Wp[idx] = (k < HDIM) ? sx[k * HDIM + j] : sh[(k - HDIM) * HDIM + j];
}

// ---------------- fused 4-gate pre-projection GEMM (fp32) ---------------- (unchanged)
#define BM 64
#define BN 64
#define BK 32

__global__ __launch_bounds__(256) void gemm_pre_kernel(
    const float* __restrict__ x, const float* __restrict__ hp,
    const float* __restrict__ Wp, const float* __restrict__ bi,
    float* __restrict__ pre) {
  __shared__ float As[BK][BM];
  __shared__ float Bs[BK][BN];
  const int tid = threadIdx.x;
  const int n0 = blockIdx.x * BN;
  const int m0 = blockIdx.y * BM;
  const int tx = tid & 15;
  const int ty = tid >> 4;
  float acc[4][4] = {{0.f}};

  for (int k0 = 0; k0 < KDIM; k0 += BK) {
    const float* asrc = (k0 < HDIM) ? (x + k0) : (hp + (k0 - HDIM));
#pragma unroll
    for (int i = 0; i < 2; ++i) {
      const int f = tid + i * 256;
      const int row = f >> 3;
      const int c4 = (f & 7) * 4;
      const float4 a = *(const float4*)(asrc + (size_t)(m0 + row) * HDIM + c4);
      As[c4 + 0][row] = a.x;
      As[c4 + 1][row] = a.y;
      As[c4 + 2][row] = a.z;
      As[c4 + 3][row] = a.w;
      const int rB = f >> 4;
      const int cB = (f & 15) * 4;
      *(float4*)&Bs[rB][cB] = *(const float4*)(Wp + (size_t)(k0 + rB) * NDIM + n0 + cB);
    }
    __syncthreads();
#pragma unroll
    for (int kk = 0; kk < BK; ++kk) {
      const float4 av = *(const float4*)&As[kk][ty * 4];
      const float4 bv = *(const float4*)&Bs[kk][tx * 4];
      const float a[4] = {av.x, av.y, av.z, av.w};
      const float b[4] = {bv.x, bv.y, bv.z, bv.w};
#pragma unroll
      for (int r = 0; r < 4; ++r)
#pragma unroll
        for (int c = 0; c < 4; ++c)
          acc[r][c] = fmaf(a[r], b[c], acc[r][c]);
    }
    __syncthreads();
  }
  const int jb = (n0 & 255) + tx * 4;
  const float4 bias = *(const float4*)(bi + jb);
#pragma unroll
  for (int r = 0; r < 4; ++r) {
    const int m = m0 + ty * 4 + r;
    float4 v;
    v.x = acc[r][0] + bias.x;
    v.y = acc[r][1] + bias.y;
    v.z = acc[r][2] + bias.z;
    v.w = acc[r][3] + bias.w;
    *(float4*)(pre + (size_t)m * NDIM + n0 + tx * 4) = v;
  }
}

// ---------------- sequential scan v5: 16 waves, K=16 per wave, J=4 per thread ----------------
// Rounds 2-6 evidence: the allocator stashes large barrier-crossing live-sets in
// AGPRs (VGPR_Count 160/104/84; VALU ~1600cy/step vs 512 FMA floor = accvgpr_read
// moves). Lever: halve per-thread u footprint to 64 floats (16 f32x4) via 1024
// threads / 16-wave k-split; per-CU FMA floor unchanged (same total work), but
// small live-set should stay in arch VGPRs, and 4 waves/SIMD hides latency.
__global__ __launch_bounds__(1024, 1) void scan_kernel(
    const float* __restrict__ pre, const float* __restrict__ ui,
    float* __restrict__ out) {
  const int b   = blockIdx.x;
  const int tid = threadIdx.x;
  const int w   = tid >> 6;   // wave id = k-split slot (0..15)
  const int cg  = tid & 63;   // column group
  __shared__ float hbuf[HDIM];
  __shared__ float rbuf[16][4][64];

  // ---- load u-slice into 16 f32x4 registers (once): k in [16w, 16w+16) ----
  const float* ub = ui + (16 * w) * HDIM + cg;   // row 16w, col cg
#define ULOAD(K) f32x4 u##K = { \
    ub[(K) * HDIM], ub[(K) * HDIM + 64], ub[(K) * HDIM + 128], ub[(K) * HDIM + 192]};
  ULOAD(0)  ULOAD(1)  ULOAD(2)  ULOAD(3)  ULOAD(4)  ULOAD(5)  ULOAD(6)  ULOAD(7)
  ULOAD(8)  ULOAD(9)  ULOAD(10) ULOAD(11) ULOAD(12) ULOAD(13) ULOAD(14) ULOAD(15)
#undef ULOAD

  const float* preb = pre + (size_t)b * TLEN * NDIM;
  float* hidden = out + 2 * BATCH * HDIM + (size_t)b * TLEN * HDIM;

  float pi = 0.f, pf = 0.f, pg = 0.f, po = 0.f;
  float c = 0.f, h = 0.f;
  if (tid < HDIM) {
    hbuf[tid] = 0.f;
    pi = preb[tid]; pf = preb[256 + tid]; pg = preb[512 + tid]; po = preb[768 + tid];
  }
  __syncthreads();

  const float* hb = &hbuf[w * 16];

  for (int t = 0; t < TLEN; ++t) {
    // pin u (kept from round 6: net +180us there even under stash-regime)
    asm volatile("" : "+v"(u0),  "+v"(u1),  "+v"(u2),  "+v"(u3));
    asm volatile("" : "+v"(u4),  "+v"(u5),  "+v"(u6),  "+v"(u7));
    asm volatile("" : "+v"(u8),  "+v"(u9),  "+v"(u10), "+v"(u11));
    asm volatile("" : "+v"(u12), "+v"(u13), "+v"(u14), "+v"(u15));

    // prefetch t+1 pre (one full step of latency hiding)
    float npi = 0.f, npf = 0.f, npg = 0.f, npo = 0.f;
    if (tid < HDIM) {
      const int tn = (t < TLEN - 1) ? t + 1 : t;
      const float* pn = preb + (size_t)tn * NDIM;
      npi = pn[tid]; npf = pn[256 + tid]; npg = pn[512 + tid]; npo = pn[768 + tid];
    }

    // ---- phase A: 16 k-steps, 4 columns each; h via wave-uniform b128 broadcast ----
    f32x4 acc = {0.f, 0.f, 0.f, 0.f};
#define KQ(K4, UA, UB, UC, UD) { \
    const f32x4 hv = *(const f32x4*)(hb + 4 * (K4)); \
    acc.x = fmaf(hv.x, UA.x, acc.x); acc.y = fmaf(hv.x, UA.y, acc.y); \
    acc.z = fmaf(hv.x, UA.z, acc.z); acc.w = fmaf(hv.x, UA.w, acc.w); \
    acc.x = fmaf(hv.y, UB.x, acc.x); acc.y = fmaf(hv.y, UB.y, acc.y); \
    acc.z = fmaf(hv.y, UB.z, acc.z); acc.w = fmaf(hv.y, UB.w, acc.w); \
    acc.x = fmaf(hv.z, UC.x, acc.x); acc.y = fmaf(hv.z, UC.y, acc.y); \
    acc.z = fmaf(hv.z, UC.z, acc.z); acc.w = fmaf(hv.z, UC.w, acc.w); \
    acc.x = fmaf(hv.w, UD.x, acc.x); acc.y = fmaf(hv.w, UD.y, acc.y); \
    acc.z = fmaf(hv.w, UD.z, acc.z); acc.w = fmaf(hv.w, UD.w, acc.w); }
    KQ(0, u0,  u1,  u2,  u3)
    KQ(1, u4,  u5,  u6,  u7)
    KQ(2, u8,  u9,  u10, u11)
    KQ(3, u12, u13, u14, u15)
#undef KQ

    // partial write: [w][jj][cg] -> lanes stride-1 in cg, conflict-free
    rbuf[w][0][cg] = acc.x;
    rbuf[w][1][cg] = acc.y;
    rbuf[w][2][cg] = acc.z;
    rbuf[w][3][cg] = acc.w;
    __syncthreads();

    // ---- phase B: waves 0-3 (thread j = tid < 256): reduce + gates + state ----
    if (tid < HDIM) {
      const int jjf = tid >> 6;   // wave-uniform -> conflict-free stride-1 reads
      const int cgf = tid & 63;
      float r = 0.f;
#pragma unroll
      for (int w2 = 0; w2 < 16; ++w2) r += rbuf[w2][jjf][cgf];

      const float gi = 1.f / (1.f + __expf(-(pi + r)));
      const float gf = 1.f / (1.f + __expf(-(pf + r)));
      const float gg = 1.f / (1.f + __expf(-(pg + r)));
      const float go = 1.f / (1.f + __expf(-(po + r)));
      c = gf + c + gi * gg;                                 // reference quirk: f + c + i*g
      const float th = 1.f - 2.f / (__expf(2.f * c) + 1.f); // tanh, inf-safe
      h = go + th;                                          // reference quirk: o + tanh(c)

      hidden[(size_t)t * HDIM + tid] = h;
      hbuf[tid] = h;                 // safe: all phase-A reads done at barrier above
      pi = npi; pf = npf; pg = npg; po = npo;
    }
    __syncthreads();                 // new h visible before next phase A
  }
  if (tid < HDIM) {
    out[b * HDIM + tid] = h;                 // h_t  [B,H]
    out[BATCH * HDIM + b * HDIM + tid] = c;  // c_t  [B,H]
  }
}

extern "C" void kernel_launch(void* const* d_in, const int* in_sizes, int n_in,
                              void* d_out, int out_size, void* d_ws, size_t ws_size,
                              hipStream_t stream) {
  const float* x   = (const float*)d_in[0];
  const float* hp  = (const float*)d_in[1];
  const float* wix = (const float*)d_in[2];
  const float* wih = (const float*)d_in[3];
  const float* wfx = (const float*)d_in[4];
  const float* wfh = (const float*)d_in[5];
  const float* wcx = (const float*)d_in[6];
  const float* wch = (const float*)d_in[7];
  const float* wox = (const float*)d_in[8];
  const float* woh = (const float*)d_in[9];
  const float* ui  = (const float*)d_in[10];
  const float* bi  = (const float*)d_in[11];
  float* out = (float*)d_out;

  // ws layout: Wp [512*1024] f32 (2 MB) | pre [65536*1024] f32 (256 MB)
  float* Wp  = (float*)d_ws;
  float* pre = (float*)d_ws + (size_t)KDIM * NDIM;

  hipLaunchKernelGGL(pack_w_kernel, dim3((KDIM * NDIM) / 256), dim3(256), 0, stream,
                     wix, wih, wfx, wfh, wcx, wch, wox, woh, Wp);
  hipLaunchKernelGGL(gemm_pre_kernel, dim3(NDIM / BN, (BATCH * TLEN) / BM), dim3(256), 0, stream,
                     x, hp, Wp, bi, pre);
  hipLaunchKernelGGL(scan_kernel, dim3(BATCH), dim3(1024), 0, stream, pre, ui, out);
}

// Round 10
// 2659.052 us; speedup vs baseline: 1.0155x; 1.0155x over previous
//
#include <hip/hip_runtime.h>
#include <cstddef>

#define BATCH 32
#define TLEN  2048
#define HDIM  256
#define KDIM  512   // IX + IH
#define NDIM  1024  // 4 gates * H
#define MDIM  (BATCH * TLEN)   // 65536

typedef float  f32x4  __attribute__((ext_vector_type(4)));
typedef short  bf16x8 __attribute__((ext_vector_type(8)));

// ======================= fast path (split-bf16 MFMA) =======================
// pre ~= A1@W1 + A1@W2 + A2@W1 (+bias), A=A1+A2 / W=W1+W2 bf16 splits.

__device__ __forceinline__ unsigned short bf16_rne(float f) {
  unsigned int u = __float_as_uint(f);
  u += 0x7FFFu + ((u >> 16) & 1u);
  return (unsigned short)(u >> 16);
}
__device__ __forceinline__ float bf16_to_f(unsigned short s) {
  return __uint_as_float((unsigned int)s << 16);
}

// A blocked: A1g/A2g [mt][kt][128][32] bf16, mt<512, kt<16
__global__ __launch_bounds__(256) void convA_kernel(
    const float* __restrict__ x, const float* __restrict__ hp,
    unsigned short* __restrict__ A1g, unsigned short* __restrict__ A2g) {
  const int g = blockIdx.x * 256 + threadIdx.x;        // 4,194,304 threads
  const size_t e0 = (size_t)g << 3;                    // 8 elems each
  const int m = (int)(e0 >> 9);
  const int k = (int)(e0 & 511);
  const float* src = (k < HDIM) ? (x + (size_t)m * HDIM + k)
                                : (hp + (size_t)m * HDIM + (k - HDIM));
  const float4 v0 = *(const float4*)(src);
  const float4 v1 = *(const float4*)(src + 4);
  float a[8] = {v0.x, v0.y, v0.z, v0.w, v1.x, v1.y, v1.z, v1.w};
  unsigned int w1[4], w2[4];
#pragma unroll
  for (int i = 0; i < 4; ++i) {
    unsigned short h0 = bf16_rne(a[2 * i]);
    unsigned short h1 = bf16_rne(a[2 * i + 1]);
    unsigned short l0 = bf16_rne(a[2 * i] - bf16_to_f(h0));
    unsigned short l1 = bf16_rne(a[2 * i + 1] - bf16_to_f(h1));
    w1[i] = (unsigned int)h0 | ((unsigned int)h1 << 16);
    w2[i] = (unsigned int)l0 | ((unsigned int)l1 << 16);
  }
  const int mt = m >> 7, mm = m & 127, kt = k >> 5, kk = k & 31;
  const size_t off = (((size_t)(mt * 16 + kt) * 128 + mm) * 32 + kk);
  *(uint4*)(A1g + off) = make_uint4(w1[0], w1[1], w1[2], w1[3]);
  *(uint4*)(A2g + off) = make_uint4(w2[0], w2[1], w2[2], w2[3]);
}

// W blocked-TRANSPOSED: W1t/W2t [nt][kt][128n][32k] bf16 (frag reads contiguous in k)
__global__ __launch_bounds__(256) void convW_kernel(
    const float* __restrict__ wix, const float* __restrict__ wih,
    const float* __restrict__ wfx, const float* __restrict__ wfh,
    const float* __restrict__ wcx, const float* __restrict__ wch,
    const float* __restrict__ wox, const float* __restrict__ woh,
    unsigned short* __restrict__ W1t, unsigned short* __restrict__ W2t) {
  const int g = blockIdx.x * 256 + threadIdx.x;        // 65536 threads
  const int n = g >> 6;
  const int kc = (g & 63) * 8;
  const int gate = n >> 8, j = n & 255;
  const float* sx; const float* sh;
  if (gate == 0)      { sx = wix; sh = wih; }
  else if (gate == 1) { sx = wfx; sh = wfh; }
  else if (gate == 2) { sx = wcx; sh = wch; }
  else                { sx = wox; sh = woh; }
  unsigned int w1[4], w2[4];
#pragma unroll
  for (int i = 0; i < 4; ++i) {
    float a0, a1;
    {
      const int k0 = kc + 2 * i, k1 = kc + 2 * i + 1;
      a0 = (k0 < HDIM) ? sx[k0 * HDIM + j] : sh[(k0 - HDIM) * HDIM + j];
      a1 = (k1 < HDIM) ? sx[k1 * HDIM + j] : sh[(k1 - HDIM) * HDIM + j];
    }
    unsigned short h0 = bf16_rne(a0), h1 = bf16_rne(a1);
    unsigned short l0 = bf16_rne(a0 - bf16_to_f(h0));
    unsigned short l1 = bf16_rne(a1 - bf16_to_f(h1));
    w1[i] = (unsigned int)h0 | ((unsigned int)h1 << 16);
    w2[i] = (unsigned int)l0 | ((unsigned int)l1 << 16);
  }
  const int nt = n >> 7, nn = n & 127, kt = kc >> 5, kk = kc & 31;
  const size_t off = (((size_t)(nt * 16 + kt) * 128 + nn) * 32 + kk);
  *(uint4*)(W1t + off) = make_uint4(w1[0], w1[1], w1[2], w1[3]);
  *(uint4*)(W2t + off) = make_uint4(w2[0], w2[1], w2[2], w2[3]);
}

#define LPITCH 40   // LDS row pitch in ushorts (32 data + 8 pad -> conflict-free)

__global__ __launch_bounds__(256) void gemm_mfma_kernel(
    const unsigned short* __restrict__ A1g, const unsigned short* __restrict__ A2g,
    const unsigned short* __restrict__ W1t, const unsigned short* __restrict__ W2t,
    const float* __restrict__ bi, float* __restrict__ pre) {
  __shared__ unsigned short sA1[128 * LPITCH], sA2[128 * LPITCH];
  __shared__ unsigned short sB1[128 * LPITCH], sB2[128 * LPITCH];
  const int tid  = threadIdx.x;
  const int lane = tid & 63;
  const int wave = tid >> 6;
  const int wr = wave >> 1, wc = wave & 1;     // 2x2 waves of 64x64
  const int l15 = lane & 15, l4 = lane >> 4;
  const int nt = blockIdx.x, mt = blockIdx.y;

  const unsigned short* Abase1 = A1g + (size_t)mt * 16 * 4096;
  const unsigned short* Abase2 = A2g + (size_t)mt * 16 * 4096;
  const unsigned short* Bbase1 = W1t + (size_t)nt * 16 * 4096;
  const unsigned short* Bbase2 = W2t + (size_t)nt * 16 * 4096;

  f32x4 acc[4][4] = {};

  for (int kt = 0; kt < 16; ++kt) {
    const size_t tb = (size_t)kt * 4096;
#pragma unroll
    for (int i = 0; i < 2; ++i) {
      const int f = tid + i * 256;                       // 512 chunks of 16B
      const int ldst = (f >> 2) * LPITCH + (f & 3) * 8;  // padded LDS offset
      *(uint4*)&sA1[ldst] = *(const uint4*)(Abase1 + tb + (size_t)f * 8);
      *(uint4*)&sA2[ldst] = *(const uint4*)(Abase2 + tb + (size_t)f * 8);
      *(uint4*)&sB1[ldst] = *(const uint4*)(Bbase1 + tb + (size_t)f * 8);
      *(uint4*)&sB2[ldst] = *(const uint4*)(Bbase2 + tb + (size_t)f * 8);
    }
    __syncthreads();

    bf16x8 a1[4], a2[4], b1[4], b2[4];
#pragma unroll
    for (int mf = 0; mf < 4; ++mf) {
      const int ao = (wr * 64 + mf * 16 + l15) * LPITCH + l4 * 8;
      a1[mf] = *(const bf16x8*)&sA1[ao];
      a2[mf] = *(const bf16x8*)&sA2[ao];
    }
#pragma unroll
    for (int nf = 0; nf < 4; ++nf) {
      const int bo = (wc * 64 + nf * 16 + l15) * LPITCH + l4 * 8;
      b1[nf] = *(const bf16x8*)&sB1[bo];
      b2[nf] = *(const bf16x8*)&sB2[bo];
    }
#pragma unroll
    for (int mf = 0; mf < 4; ++mf)
#pragma unroll
      for (int nf = 0; nf < 4; ++nf) {
        acc[mf][nf] = __builtin_amdgcn_mfma_f32_16x16x32_bf16(a1[mf], b1[nf], acc[mf][nf], 0, 0, 0);
        acc[mf][nf] = __builtin_amdgcn_mfma_f32_16x16x32_bf16(a1[mf], b2[nf], acc[mf][nf], 0, 0, 0);
        acc[mf][nf] = __builtin_amdgcn_mfma_f32_16x16x32_bf16(a2[mf], b1[nf], acc[mf][nf], 0, 0, 0);
      }
    __syncthreads();
  }

  // epilogue: C/D layout (m89-verified): col = lane&15, row = (lane>>4)*4 + reg
#pragma unroll
  for (int nf = 0; nf < 4; ++nf) {
    const int n = nt * 128 + wc * 64 + nf * 16 + l15;
    const float bias = bi[n & 255];
#pragma unroll
    for (int mf = 0; mf < 4; ++mf) {
      const int m0 = mt * 128 + wr * 64 + mf * 16 + l4 * 4;
#pragma unroll
      for (int r = 0; r < 4; ++r)
        pre[(size_t)(m0 + r) * NDIM + n] = acc[mf][nf][r] + bias;
    }
  }
}

// ======================= fallback path (proven fp32) =======================
__global__ void pack_w_kernel(const float* __restrict__ wix, const float* __restrict__ wih,
                              const float* __restrict__ wfx, const float* __restrict__ wfh,
                              const float* __restrict__ wcx, const float* __restrict__ wch,
                              const float* __restrict__ wox, const float* __restrict__ woh,
                              float* __restrict__ Wp) {
  int idx = blockIdx.x * blockDim.x + threadIdx.x;
  if (idx >= KDIM * NDIM) return;
  int n = idx & (NDIM - 1);
  int k = idx >> 10;
  int gate = n >> 8;
  int j = n & 255;
  const float* sx; const float* sh;
  if (gate == 0)      { sx = wix; sh = wih; }
  else if (gate == 1) { sx = wfx; sh = wfh; }
  else if (gate == 2) { sx = wcx; sh = wch; }
  else                { sx = wox; sh = woh; }
  Wp[idx] = (k < HDIM) ? sx[k * HDIM + j] : sh[(k - HDIM) * HDIM + j];
}

#define BM 64
#define BN 64
#define BK 32
__global__ __launch_bounds__(256) void gemm_pre_kernel(
    const float* __restrict__ x, const float* __restrict__ hp,
    const float* __restrict__ Wp, const float* __restrict__ bi,
    float* __restrict__ pre) {
  __shared__ float As[BK][BM];
  __shared__ float Bs[BK][BN];
  const int tid = threadIdx.x;
  const int n0 = blockIdx.x * BN;
  const int m0 = blockIdx.y * BM;
  const int tx = tid & 15;
  const int ty = tid >> 4;
  float acc[4][4] = {{0.f}};
  for (int k0 = 0; k0 < KDIM; k0 += BK) {
    const float* asrc = (k0 < HDIM) ? (x + k0) : (hp + (k0 - HDIM));
#pragma unroll
    for (int i = 0; i < 2; ++i) {
      const int f = tid + i * 256;
      const int row = f >> 3;
      const int c4 = (f & 7) * 4;
      const float4 a = *(const float4*)(asrc + (size_t)(m0 + row) * HDIM + c4);
      As[c4 + 0][row] = a.x;
      As[c4 + 1][row] = a.y;
      As[c4 + 2][row] = a.z;
      As[c4 + 3][row] = a.w;
      const int rB = f >> 4;
      const int cB = (f & 15) * 4;
      *(float4*)&Bs[rB][cB] = *(const float4*)(Wp + (size_t)(k0 + rB) * NDIM + n0 + cB);
    }
    __syncthreads();
#pragma unroll
    for (int kk = 0; kk < BK; ++kk) {
      const float4 av = *(const float4*)&As[kk][ty * 4];
      const float4 bv = *(const float4*)&Bs[kk][tx * 4];
      const float a[4] = {av.x, av.y, av.z, av.w};
      const float b[4] = {bv.x, bv.y, bv.z, bv.w};
#pragma unroll
      for (int r = 0; r < 4; ++r)
#pragma unroll
        for (int c = 0; c < 4; ++c)
          acc[r][c] = fmaf(a[r], b[c], acc[r][c]);
    }
    __syncthreads();
  }
  const int jb = (n0 & 255) + tx * 4;
  const float4 bias = *(const float4*)(bi + jb);
#pragma unroll
  for (int r = 0; r < 4; ++r) {
    const int m = m0 + ty * 4 + r;
    float4 v;
    v.x = acc[r][0] + bias.x;
    v.y = acc[r][1] + bias.y;
    v.z = acc[r][2] + bias.z;
    v.w = acc[r][3] + bias.w;
    *(float4*)(pre + (size_t)m * NDIM + n0 + tx * 4) = v;
  }
}

// ---------------- sequential scan (round-6 best: 512 thr, 8-wave k-split) ----------------
__global__ __launch_bounds__(512, 2) void scan_kernel(
    const float* __restrict__ pre, const float* __restrict__ ui,
    float* __restrict__ out) {
  const int b   = blockIdx.x;
  const int tid = threadIdx.x;
  const int w   = tid >> 6;
  const int cg  = tid & 63;
  __shared__ float hbuf[HDIM];
  __shared__ float rbuf[8][4][64];

  const float* ub = ui + (32 * w) * HDIM + cg;
#define ULOAD(K) f32x4 u##K = { \
    ub[(K) * HDIM], ub[(K) * HDIM + 64], ub[(K) * HDIM + 128], ub[(K) * HDIM + 192]};
  ULOAD(0)  ULOAD(1)  ULOAD(2)  ULOAD(3)  ULOAD(4)  ULOAD(5)  ULOAD(6)  ULOAD(7)
  ULOAD(8)  ULOAD(9)  ULOAD(10) ULOAD(11) ULOAD(12) ULOAD(13) ULOAD(14) ULOAD(15)
  ULOAD(16) ULOAD(17) ULOAD(18) ULOAD(19) ULOAD(20) ULOAD(21) ULOAD(22) ULOAD(23)
  ULOAD(24) ULOAD(25) ULOAD(26) ULOAD(27) ULOAD(28) ULOAD(29) ULOAD(30) ULOAD(31)
#undef ULOAD

  const float* preb = pre + (size_t)b * TLEN * NDIM;
  float* hidden = out + 2 * BATCH * HDIM + (size_t)b * TLEN * HDIM;

  float pi = 0.f, pf = 0.f, pg = 0.f, po = 0.f;
  float c = 0.f, h = 0.f;
  if (tid < HDIM) {
    hbuf[tid] = 0.f;
    pi = preb[tid]; pf = preb[256 + tid]; pg = preb[512 + tid]; po = preb[768 + tid];
  }
  __syncthreads();

  const float* hb = &hbuf[w * 32];

  for (int t = 0; t < TLEN; ++t) {
    asm volatile("" : "+v"(u0),  "+v"(u1),  "+v"(u2),  "+v"(u3));
    asm volatile("" : "+v"(u4),  "+v"(u5),  "+v"(u6),  "+v"(u7));
    asm volatile("" : "+v"(u8),  "+v"(u9),  "+v"(u10), "+v"(u11));
    asm volatile("" : "+v"(u12), "+v"(u13), "+v"(u14), "+v"(u15));
    asm volatile("" : "+v"(u16), "+v"(u17), "+v"(u18), "+v"(u19));
    asm volatile("" : "+v"(u20), "+v"(u21), "+v"(u22), "+v"(u23));
    asm volatile("" : "+v"(u24), "+v"(u25), "+v"(u26), "+v"(u27));
    asm volatile("" : "+v"(u28), "+v"(u29), "+v"(u30), "+v"(u31));

    float npi = 0.f, npf = 0.f, npg = 0.f, npo = 0.f;
    if (tid < HDIM) {
      const int tn = (t < TLEN - 1) ? t + 1 : t;
      const float* pn = preb + (size_t)tn * NDIM;
      npi = pn[tid]; npf = pn[256 + tid]; npg = pn[512 + tid]; npo = pn[768 + tid];
    }

    f32x4 acc = {0.f, 0.f, 0.f, 0.f};
#define KQ(K4, UA, UB, UC, UD) { \
    const f32x4 hv = *(const f32x4*)(hb + 4 * (K4)); \
    acc.x = fmaf(hv.x, UA.x, acc.x); acc.y = fmaf(hv.x, UA.y, acc.y); \
    acc.z = fmaf(hv.x, UA.z, acc.z); acc.w = fmaf(hv.x, UA.w, acc.w); \
    acc.x = fmaf(hv.y, UB.x, acc.x); acc.y = fmaf(hv.y, UB.y, acc.y); \
    acc.z = fmaf(hv.y, UB.z, acc.z); acc.w = fmaf(hv.y, UB.w, acc.w); \
    acc.x = fmaf(hv.z, UC.x, acc.x); acc.y = fmaf(hv.z, UC.y, acc.y); \
    acc.z = fmaf(hv.z, UC.z, acc.z); acc.w = fmaf(hv.z, UC.w, acc.w); \
    acc.x = fmaf(hv.w, UD.x, acc.x); acc.y = fmaf(hv.w, UD.y, acc.y); \
    acc.z = fmaf(hv.w, UD.z, acc.z); acc.w = fmaf(hv.w, UD.w, acc.w); }
    KQ(0, u0,  u1,  u2,  u3)
    KQ(1, u4,  u5,  u6,  u7)
    KQ(2, u8,  u9,  u10, u11)
    KQ(3, u12, u13, u14, u15)
    KQ(4, u16, u17, u18, u19)
    KQ(5, u20, u21, u22, u23)
    KQ(6, u24, u25, u26, u27)
    KQ(7, u28, u29, u30, u31)
#undef KQ

    rbuf[w][0][cg] = acc.x;
    rbuf[w][1][cg] = acc.y;
    rbuf[w][2][cg] = acc.z;
    rbuf[w][3][cg] = acc.w;
    __syncthreads();

    if (tid < HDIM) {
      const int jjf = tid >> 6;
      const int cgf = tid & 63;
      float r = 0.f;
#pragma unroll
      for (int w2 = 0; w2 < 8; ++w2) r += rbuf[w2][jjf][cgf];

      const float gi = 1.f / (1.f + __expf(-(pi + r)));
      const float gf = 1.f / (1.f + __expf(-(pf + r)));
      const float gg = 1.f / (1.f + __expf(-(pg + r)));
      const float go = 1.f / (1.f + __expf(-(po + r)));
      c = gf + c + gi * gg;                                 // quirk: f + c + i*g
      const float th = 1.f - 2.f / (__expf(2.f * c) + 1.f); // tanh, inf-safe
      h = go + th;                                          // quirk: o + tanh(c)

      hidden[(size_t)t * HDIM + tid] = h;
      hbuf[tid] = h;
      pi = npi; pf = npf; pg = npg; po = npo;
    }
    __syncthreads();
  }
  if (tid < HDIM) {
    out[b * HDIM + tid] = h;
    out[BATCH * HDIM + b * HDIM + tid] = c;
  }
}

extern "C" void kernel_launch(void* const* d_in, const int* in_sizes, int n_in,
                              void* d_out, int out_size, void* d_ws, size_t ws_size,
                              hipStream_t stream) {
  const float* x   = (const float*)d_in[0];
  const float* hp  = (const float*)d_in[1];
  const float* wix = (const float*)d_in[2];
  const float* wih = (const float*)d_in[3];
  const float* wfx = (const float*)d_in[4];
  const float* wfh = (const float*)d_in[5];
  const float* wcx = (const float*)d_in[6];
  const float* wch = (const float*)d_in[7];
  const float* wox = (const float*)d_in[8];
  const float* woh = (const float*)d_in[9];
  const float* ui  = (const float*)d_in[10];
  const float* bi  = (const float*)d_in[11];
  float* out = (float*)d_out;

  // ws layout: pre [65536*1024] f32 (256 MB) first (both paths), then path scratch.
  float* pre = (float*)d_ws;
  const size_t preB = (size_t)MDIM * NDIM * 4;                 // 256 MB
  const size_t a1B  = (size_t)MDIM * KDIM * 2;                 // 64 MB
  const size_t wtB  = (size_t)KDIM * NDIM * 2;                 // 1 MB
  const size_t needFast = preB + 2 * a1B + 2 * wtB;            // ~386 MB

  if (ws_size >= needFast) {
    unsigned short* A1g = (unsigned short*)((char*)d_ws + preB);
    unsigned short* A2g = (unsigned short*)((char*)d_ws + preB + a1B);
    unsigned short* W1t = (unsigned short*)((char*)d_ws + preB + 2 * a1B);
    unsigned short* W2t = (unsigned short*)((char*)d_ws + preB + 2 * a1B + wtB);
    hipLaunchKernelGGL(convA_kernel, dim3(MDIM * KDIM / 8 / 256), dim3(256), 0, stream,
                       x, hp, A1g, A2g);
    hipLaunchKernelGGL(convW_kernel, dim3(KDIM * NDIM / 8 / 256), dim3(256), 0, stream,
                       wix, wih, wfx, wfh, wcx, wch, wox, woh, W1t, W2t);
    hipLaunchKernelGGL(gemm_mfma_kernel, dim3(NDIM / 128, MDIM / 128), dim3(256), 0, stream,
                       A1g, A2g, W1t, W2t, bi, pre);
  } else {
    float* Wp = (float*)((char*)d_ws + preB);
    hipLaunchKernelGGL(pack_w_kernel, dim3((KDIM * NDIM) / 256), dim3(256), 0, stream,
                       wix, wih, wfx, wfh, wcx, wch, wox, woh, Wp);
    hipLaunchKernelGGL(gemm_pre_kernel, dim3(NDIM / BN, MDIM / BM), dim3(256), 0, stream,
                       x, hp, Wp, bi, pre);
  }
  hipLaunchKernelGGL(scan_kernel, dim3(BATCH), dim3(512), 0, stream, pre, ui, out);
}

// Round 11
// 1909.048 us; speedup vs baseline: 1.4145x; 1.3929x over previous
//
#include <hip/hip_runtime.h>
#include <cstddef>

#define BATCH 32
#define TLEN  2048
#define HDIM  256
#define KDIM  512   // IX + IH
#define NDIM  1024  // 4 gates * H
#define MDIM  (BATCH * TLEN)   // 65536

typedef float  f32x4  __attribute__((ext_vector_type(4)));
typedef short  bf16x8 __attribute__((ext_vector_type(8)));

// ======================= split-bf16 MFMA pre-projection =======================
// pre ~= A1@W1 + A1@W2 + A2@W1 (+bias); A=A1+A2, W=W1+W2 bf16 hi/lo splits.
// A is split ON THE FLY in the GEMM staging phase (no 128MB A scratch; ws_size
// is only known to be >= 258MB -- round-10 gate proved < 386MB).

__device__ __forceinline__ unsigned short bf16_rne(float f) {
  unsigned int u = __float_as_uint(f);
  u += 0x7FFFu + ((u >> 16) & 1u);
  return (unsigned short)(u >> 16);
}
__device__ __forceinline__ float bf16_to_f(unsigned short s) {
  return __uint_as_float((unsigned int)s << 16);
}

// W blocked-TRANSPOSED: W1t/W2t [nt][kt][128n][32k] bf16 (frag reads contiguous in k)
__global__ __launch_bounds__(256) void convW_kernel(
    const float* __restrict__ wix, const float* __restrict__ wih,
    const float* __restrict__ wfx, const float* __restrict__ wfh,
    const float* __restrict__ wcx, const float* __restrict__ wch,
    const float* __restrict__ wox, const float* __restrict__ woh,
    unsigned short* __restrict__ W1t, unsigned short* __restrict__ W2t) {
  const int g = blockIdx.x * 256 + threadIdx.x;        // 65536 threads
  const int n = g >> 6;
  const int kc = (g & 63) * 8;
  const int gate = n >> 8, j = n & 255;
  const float* sx; const float* sh;
  if (gate == 0)      { sx = wix; sh = wih; }
  else if (gate == 1) { sx = wfx; sh = wfh; }
  else if (gate == 2) { sx = wcx; sh = wch; }
  else                { sx = wox; sh = woh; }
  unsigned int w1[4], w2[4];
#pragma unroll
  for (int i = 0; i < 4; ++i) {
    float a0, a1;
    {
      const int k0 = kc + 2 * i, k1 = kc + 2 * i + 1;
      a0 = (k0 < HDIM) ? sx[k0 * HDIM + j] : sh[(k0 - HDIM) * HDIM + j];
      a1 = (k1 < HDIM) ? sx[k1 * HDIM + j] : sh[(k1 - HDIM) * HDIM + j];
    }
    unsigned short h0 = bf16_rne(a0), h1 = bf16_rne(a1);
    unsigned short l0 = bf16_rne(a0 - bf16_to_f(h0));
    unsigned short l1 = bf16_rne(a1 - bf16_to_f(h1));
    w1[i] = (unsigned int)h0 | ((unsigned int)h1 << 16);
    w2[i] = (unsigned int)l0 | ((unsigned int)l1 << 16);
  }
  const int nt = n >> 7, kt = kc >> 5, kk = kc & 31;
  const int nn = n & 127;
  const size_t off = (((size_t)(nt * 16 + kt) * 128 + nn) * 32 + kk);
  *(uint4*)(W1t + off) = make_uint4(w1[0], w1[1], w1[2], w1[3]);
  *(uint4*)(W2t + off) = make_uint4(w2[0], w2[1], w2[2], w2[3]);
}

#define LPITCH 40   // LDS row pitch in ushorts (32 data + 8 pad)

__global__ __launch_bounds__(256) void gemm_mfma2_kernel(
    const float* __restrict__ x, const float* __restrict__ hp,
    const unsigned short* __restrict__ W1t, const unsigned short* __restrict__ W2t,
    const float* __restrict__ bi, float* __restrict__ pre) {
  __shared__ unsigned short sA1[128 * LPITCH], sA2[128 * LPITCH];
  __shared__ unsigned short sB1[128 * LPITCH], sB2[128 * LPITCH];
  const int tid  = threadIdx.x;
  const int lane = tid & 63;
  const int wave = tid >> 6;
  const int wr = wave >> 1, wc = wave & 1;     // 2x2 waves of 64x64
  const int l15 = lane & 15, l4 = lane >> 4;

  // XCD-coherent decode: all 8 nt-blocks of one mt share p%8 -> same XCD L2
  // p = (mt%8) + 8*((mt/8)*8 + nt)  =>  r=p%8; s=p/8; nt=s%8; mt=(s/8)*8+r
  const int p = blockIdx.x;
  const int r8 = p & 7;
  const int s  = p >> 3;
  const int nt = s & 7;
  const int mt = (s >> 3) * 8 + r8;

  const unsigned short* Bbase1 = W1t + (size_t)nt * 16 * 4096;
  const unsigned short* Bbase2 = W2t + (size_t)nt * 16 * 4096;

  f32x4 acc[4][4] = {};

  for (int kt = 0; kt < 16; ++kt) {
    // ---- A: load f32 tile (128 x 32, row stride 256), split to bf16 hi/lo ----
    const float* asrc = (kt < 8)
        ? (x  + (size_t)(mt * 128) * HDIM + kt * 32)
        : (hp + (size_t)(mt * 128) * HDIM + (kt - 8) * 32);
#pragma unroll
    for (int i = 0; i < 4; ++i) {
      const int q = tid + i * 256;          // 1024 float4 chunks
      const int row = q >> 3;
      const int c4 = (q & 7) * 4;
      const f32x4 a = *(const f32x4*)(asrc + (size_t)row * HDIM + c4);
      const unsigned short h0 = bf16_rne(a.x), h1 = bf16_rne(a.y);
      const unsigned short h2 = bf16_rne(a.z), h3 = bf16_rne(a.w);
      const unsigned short g0 = bf16_rne(a.x - bf16_to_f(h0));
      const unsigned short g1 = bf16_rne(a.y - bf16_to_f(h1));
      const unsigned short g2 = bf16_rne(a.z - bf16_to_f(h2));
      const unsigned short g3 = bf16_rne(a.w - bf16_to_f(h3));
      const int ld = row * LPITCH + c4;
      *(uint2*)&sA1[ld] = make_uint2((unsigned int)h0 | ((unsigned int)h1 << 16),
                                     (unsigned int)h2 | ((unsigned int)h3 << 16));
      *(uint2*)&sA2[ld] = make_uint2((unsigned int)g0 | ((unsigned int)g1 << 16),
                                     (unsigned int)g2 | ((unsigned int)g3 << 16));
    }
    // ---- B: pre-split bf16 tiles, blocked [kt][128][32] ----
    const size_t tb = (size_t)kt * 4096;
#pragma unroll
    for (int i = 0; i < 2; ++i) {
      const int f = tid + i * 256;                       // 512 chunks of 16B
      const int ldst = (f >> 2) * LPITCH + (f & 3) * 8;
      *(uint4*)&sB1[ldst] = *(const uint4*)(Bbase1 + tb + (size_t)f * 8);
      *(uint4*)&sB2[ldst] = *(const uint4*)(Bbase2 + tb + (size_t)f * 8);
    }
    __syncthreads();

    bf16x8 a1[4], a2[4], b1[4], b2[4];
#pragma unroll
    for (int mf = 0; mf < 4; ++mf) {
      const int ao = (wr * 64 + mf * 16 + l15) * LPITCH + l4 * 8;
      a1[mf] = *(const bf16x8*)&sA1[ao];
      a2[mf] = *(const bf16x8*)&sA2[ao];
    }
#pragma unroll
    for (int nf = 0; nf < 4; ++nf) {
      const int bo = (wc * 64 + nf * 16 + l15) * LPITCH + l4 * 8;
      b1[nf] = *(const bf16x8*)&sB1[bo];
      b2[nf] = *(const bf16x8*)&sB2[bo];
    }
#pragma unroll
    for (int mf = 0; mf < 4; ++mf)
#pragma unroll
      for (int nf = 0; nf < 4; ++nf) {
        acc[mf][nf] = __builtin_amdgcn_mfma_f32_16x16x32_bf16(a1[mf], b1[nf], acc[mf][nf], 0, 0, 0);
        acc[mf][nf] = __builtin_amdgcn_mfma_f32_16x16x32_bf16(a1[mf], b2[nf], acc[mf][nf], 0, 0, 0);
        acc[mf][nf] = __builtin_amdgcn_mfma_f32_16x16x32_bf16(a2[mf], b1[nf], acc[mf][nf], 0, 0, 0);
      }
    __syncthreads();
  }

  // epilogue: C/D layout (m89): col(n) = lane&15, row(m) = (lane>>4)*4 + reg
#pragma unroll
  for (int nf = 0; nf < 4; ++nf) {
    const int n = nt * 128 + wc * 64 + nf * 16 + l15;
    const float bias = bi[n & 255];
#pragma unroll
    for (int mf = 0; mf < 4; ++mf) {
      const int m0 = mt * 128 + wr * 64 + mf * 16 + l4 * 4;
#pragma unroll
      for (int rr = 0; rr < 4; ++rr)
        pre[(size_t)(m0 + rr) * NDIM + n] = acc[mf][nf][rr] + bias;
    }
  }
}

// ---------------- sequential scan (round-6 best: 512 thr, 8-wave k-split) ----------------
__global__ __launch_bounds__(512, 2) void scan_kernel(
    const float* __restrict__ pre, const float* __restrict__ ui,
    float* __restrict__ out) {
  const int b   = blockIdx.x;
  const int tid = threadIdx.x;
  const int w   = tid >> 6;
  const int cg  = tid & 63;
  __shared__ float hbuf[HDIM];
  __shared__ float rbuf[8][4][64];

  const float* ub = ui + (32 * w) * HDIM + cg;
#define ULOAD(K) f32x4 u##K = { \
    ub[(K) * HDIM], ub[(K) * HDIM + 64], ub[(K) * HDIM + 128], ub[(K) * HDIM + 192]};
  ULOAD(0)  ULOAD(1)  ULOAD(2)  ULOAD(3)  ULOAD(4)  ULOAD(5)  ULOAD(6)  ULOAD(7)
  ULOAD(8)  ULOAD(9)  ULOAD(10) ULOAD(11) ULOAD(12) ULOAD(13) ULOAD(14) ULOAD(15)
  ULOAD(16) ULOAD(17) ULOAD(18) ULOAD(19) ULOAD(20) ULOAD(21) ULOAD(22) ULOAD(23)
  ULOAD(24) ULOAD(25) ULOAD(26) ULOAD(27) ULOAD(28) ULOAD(29) ULOAD(30) ULOAD(31)
#undef ULOAD

  const float* preb = pre + (size_t)b * TLEN * NDIM;
  float* hidden = out + 2 * BATCH * HDIM + (size_t)b * TLEN * HDIM;

  float pi = 0.f, pf = 0.f, pg = 0.f, po = 0.f;
  float c = 0.f, h = 0.f;
  if (tid < HDIM) {
    hbuf[tid] = 0.f;
    pi = preb[tid]; pf = preb[256 + tid]; pg = preb[512 + tid]; po = preb[768 + tid];
  }
  __syncthreads();

  const float* hb = &hbuf[w * 32];

  for (int t = 0; t < TLEN; ++t) {
    asm volatile("" : "+v"(u0),  "+v"(u1),  "+v"(u2),  "+v"(u3));
    asm volatile("" : "+v"(u4),  "+v"(u5),  "+v"(u6),  "+v"(u7));
    asm volatile("" : "+v"(u8),  "+v"(u9),  "+v"(u10), "+v"(u11));
    asm volatile("" : "+v"(u12), "+v"(u13), "+v"(u14), "+v"(u15));
    asm volatile("" : "+v"(u16), "+v"(u17), "+v"(u18), "+v"(u19));
    asm volatile("" : "+v"(u20), "+v"(u21), "+v"(u22), "+v"(u23));
    asm volatile("" : "+v"(u24), "+v"(u25), "+v"(u26), "+v"(u27));
    asm volatile("" : "+v"(u28), "+v"(u29), "+v"(u30), "+v"(u31));

    float npi = 0.f, npf = 0.f, npg = 0.f, npo = 0.f;
    if (tid < HDIM) {
      const int tn = (t < TLEN - 1) ? t + 1 : t;
      const float* pn = preb + (size_t)tn * NDIM;
      npi = pn[tid]; npf = pn[256 + tid]; npg = pn[512 + tid]; npo = pn[768 + tid];
    }

    f32x4 acc = {0.f, 0.f, 0.f, 0.f};
#define KQ(K4, UA, UB, UC, UD) { \
    const f32x4 hv = *(const f32x4*)(hb + 4 * (K4)); \
    acc.x = fmaf(hv.x, UA.x, acc.x); acc.y = fmaf(hv.x, UA.y, acc.y); \
    acc.z = fmaf(hv.x, UA.z, acc.z); acc.w = fmaf(hv.x, UA.w, acc.w); \
    acc.x = fmaf(hv.y, UB.x, acc.x); acc.y = fmaf(hv.y, UB.y, acc.y); \
    acc.z = fmaf(hv.y, UB.z, acc.z); acc.w = fmaf(hv.y, UB.w, acc.w); \
    acc.x = fmaf(hv.z, UC.x, acc.x); acc.y = fmaf(hv.z, UC.y, acc.y); \
    acc.z = fmaf(hv.z, UC.z, acc.z); acc.w = fmaf(hv.z, UC.w, acc.w); \
    acc.x = fmaf(hv.w, UD.x, acc.x); acc.y = fmaf(hv.w, UD.y, acc.y); \
    acc.z = fmaf(hv.w, UD.z, acc.z); acc.w = fmaf(hv.w, UD.w, acc.w); }
    KQ(0, u0,  u1,  u2,  u3)
    KQ(1, u4,  u5,  u6,  u7)
    KQ(2, u8,  u9,  u10, u11)
    KQ(3, u12, u13, u14, u15)
    KQ(4, u16, u17, u18, u19)
    KQ(5, u20, u21, u22, u23)
    KQ(6, u24, u25, u26, u27)
    KQ(7, u28, u29, u30, u31)
#undef KQ

    rbuf[w][0][cg] = acc.x;
    rbuf[w][1][cg] = acc.y;
    rbuf[w][2][cg] = acc.z;
    rbuf[w][3][cg] = acc.w;
    __syncthreads();

    if (tid < HDIM) {
      const int jjf = tid >> 6;
      const int cgf = tid & 63;
      float r = 0.f;
#pragma unroll
      for (int w2 = 0; w2 < 8; ++w2) r += rbuf[w2][jjf][cgf];

      const float gi = 1.f / (1.f + __expf(-(pi + r)));
      const float gf = 1.f / (1.f + __expf(-(pf + r)));
      const float gg = 1.f / (1.f + __expf(-(pg + r)));
      const float go = 1.f / (1.f + __expf(-(po + r)));
      c = gf + c + gi * gg;                                 // quirk: f + c + i*g
      const float th = 1.f - 2.f / (__expf(2.f * c) + 1.f); // tanh, inf-safe
      h = go + th;                                          // quirk: o + tanh(c)

      hidden[(size_t)t * HDIM + tid] = h;
      hbuf[tid] = h;
      pi = npi; pf = npf; pg = npg; po = npo;
    }
    __syncthreads();
  }
  if (tid < HDIM) {
    out[b * HDIM + tid] = h;
    out[BATCH * HDIM + b * HDIM + tid] = c;
  }
}

extern "C" void kernel_launch(void* const* d_in, const int* in_sizes, int n_in,
                              void* d_out, int out_size, void* d_ws, size_t ws_size,
                              hipStream_t stream) {
  const float* x   = (const float*)d_in[0];
  const float* hp  = (const float*)d_in[1];
  const float* wix = (const float*)d_in[2];
  const float* wih = (const float*)d_in[3];
  const float* wfx = (const float*)d_in[4];
  const float* wfh = (const float*)d_in[5];
  const float* wcx = (const float*)d_in[6];
  const float* wch = (const float*)d_in[7];
  const float* wox = (const float*)d_in[8];
  const float* woh = (const float*)d_in[9];
  const float* ui  = (const float*)d_in[10];
  const float* bi  = (const float*)d_in[11];
  float* out = (float*)d_out;

  // ws layout: pre [65536*1024] f32 (256 MB) | W1t (1 MB) | W2t (1 MB)  = 258 MB
  // (proven available: rounds 2-10 placed 2 MB of Wp at the same offset)
  float* pre = (float*)d_ws;
  const size_t preB = (size_t)MDIM * NDIM * 4;
  const size_t wtB  = (size_t)KDIM * NDIM * 2;
  unsigned short* W1t = (unsigned short*)((char*)d_ws + preB);
  unsigned short* W2t = (unsigned short*)((char*)d_ws + preB + wtB);

  hipLaunchKernelGGL(convW_kernel, dim3(KDIM * NDIM / 8 / 256), dim3(256), 0, stream,
                     wix, wih, wfx, wfh, wcx, wch, wox, woh, W1t, W2t);
  hipLaunchKernelGGL(gemm_mfma2_kernel, dim3((NDIM / 128) * (MDIM / 128)), dim3(256), 0, stream,
                     x, hp, W1t, W2t, bi, pre);
  hipLaunchKernelGGL(scan_kernel, dim3(BATCH), dim3(512), 0, stream, pre, ui, out);
}